// Round 2
// baseline (43.925 us; speedup 1.0000x reference)
//
#include <hip/hip_runtime.h>

#define NN   50000      // nodes per graph
#define TOT  400000     // B*N total nodes
#define FI   64         // in features
#define HD   16         // hidden dim

// Key insight: edge_index.expand(B,2,E).reshape(2,-1) makes row==col
// elementwise (flat idx = b*2E + r*E + e; +8E only shifts b by 4).
// Every edge is a self-edge, so GCNConv's symmetric-normalized aggregation
// collapses to deg*dinv^2*h = h: the conv is identity + bias.
// Full network = per-node MLP: relu(relu(x@W1+b1)@W2+b2)@Wfc + bfc.
__global__ void k_mlp(const float* __restrict__ x,
                      const float* __restrict__ W1, const float* __restrict__ b1,
                      const float* __restrict__ W2, const float* __restrict__ b2,
                      const float* __restrict__ Wfc, const float* __restrict__ bfc,
                      float* __restrict__ out) {
    __shared__ float w1[FI * HD];   // 4 KB
    __shared__ float w2[HD * HD];   // 1 KB
    __shared__ float bb1[HD], bb2[HD], wf[HD];
    __shared__ float bf;
    for (int i = threadIdx.x; i < FI * HD; i += blockDim.x) w1[i] = W1[i];
    for (int i = threadIdx.x; i < HD * HD; i += blockDim.x) w2[i] = W2[i];
    if (threadIdx.x < HD) {
        bb1[threadIdx.x] = b1[threadIdx.x];
        bb2[threadIdx.x] = b2[threadIdx.x];
        wf[threadIdx.x]  = Wfc[threadIdx.x];
    }
    if (threadIdx.x == 0) bf = bfc[0];
    __syncthreads();

    int node = blockIdx.x * blockDim.x + threadIdx.x;
    if (node >= TOT) return;

    // ---- layer 1: h1 = relu(x @ W1 + b1) ----
    const float4* xr = reinterpret_cast<const float4*>(x + (size_t)node * FI);
    float acc[HD];
#pragma unroll
    for (int j = 0; j < HD; ++j) acc[j] = bb1[j];
#pragma unroll
    for (int k4 = 0; k4 < FI / 4; ++k4) {
        float4 v = xr[k4];
        float xs[4] = {v.x, v.y, v.z, v.w};
#pragma unroll
        for (int kk = 0; kk < 4; ++kk) {
            float xv = xs[kk];
            const float* wr = &w1[(k4 * 4 + kk) * HD];
#pragma unroll
            for (int j = 0; j < HD; ++j) acc[j] = fmaf(xv, wr[j], acc[j]);
        }
    }
    float h1[HD];
#pragma unroll
    for (int j = 0; j < HD; ++j) h1[j] = acc[j] > 0.0f ? acc[j] : 0.0f;

    // ---- layer 2: h2 = relu(h1 @ W2 + b2) ----
    float acc2[HD];
#pragma unroll
    for (int j = 0; j < HD; ++j) acc2[j] = bb2[j];
#pragma unroll
    for (int k = 0; k < HD; ++k) {
        float hk = h1[k];
        const float* wr = &w2[k * HD];
#pragma unroll
        for (int j = 0; j < HD; ++j) acc2[j] = fmaf(hk, wr[j], acc2[j]);
    }

    // ---- head: out = relu(h2) @ Wfc + bfc ----
    float s = bf;
#pragma unroll
    for (int j = 0; j < HD; ++j) {
        float v = acc2[j] > 0.0f ? acc2[j] : 0.0f;
        s = fmaf(v, wf[j], s);
    }
    out[node] = s;
}

extern "C" void kernel_launch(void* const* d_in, const int* in_sizes, int n_in,
                              void* d_out, int out_size, void* d_ws, size_t ws_size,
                              hipStream_t stream) {
    const float* x   = (const float*)d_in[0];
    // d_in[1] = edge_index — unused: row==col makes the conv identity+bias.
    const float* W1  = (const float*)d_in[2];
    const float* b1  = (const float*)d_in[3];
    const float* W2  = (const float*)d_in[4];
    const float* b2  = (const float*)d_in[5];
    const float* Wfc = (const float*)d_in[6];
    const float* bfc = (const float*)d_in[7];
    float* out = (float*)d_out;

    const int bs = 256;
    k_mlp<<<(TOT + bs - 1) / bs, bs, 0, stream>>>(x, W1, b1, W2, b2, Wfc, bfc, out);
}

// Round 3
// 30.838 us; speedup vs baseline: 1.4244x; 1.4244x over previous
//
#include <hip/hip_runtime.h>

#define NN   50000      // nodes per graph
#define TOT  400000     // B*N total nodes
#define FI   64         // in features
#define HD   16         // hidden dim

// edge_index.expand(B,2,E).reshape(2,-1) makes row==col elementwise
// (flat idx = b*2E + r*E + e; +8E only shifts b by 4), so every edge is a
// self-edge and GCNConv collapses to identity + bias.
// Network = per-node MLP: relu(relu(x@W1+b1)@W2+b2)@Wfc + bfc.
//
// All weight/bias accesses use wave-uniform indices -> compiler scalarizes
// to s_load (SGPR operands to v_fma), keeping the LDS pipe idle and the
// VALU fed. No __shared__ anywhere.
__global__ __launch_bounds__(256) void k_mlp(
        const float* __restrict__ x,
        const float* __restrict__ W1, const float* __restrict__ b1,
        const float* __restrict__ W2, const float* __restrict__ b2,
        const float* __restrict__ Wfc, const float* __restrict__ bfc,
        float* __restrict__ out) {
    int node = blockIdx.x * blockDim.x + threadIdx.x;
    if (node >= TOT) return;

    // ---- layer 1: h1 = relu(x @ W1 + b1) ----
    const float4* xr = reinterpret_cast<const float4*>(x + (size_t)node * FI);
    float acc[HD];
#pragma unroll
    for (int j = 0; j < HD; ++j) acc[j] = b1[j];          // uniform -> s_load
#pragma unroll
    for (int k4 = 0; k4 < FI / 4; ++k4) {
        float4 v = xr[k4];
        float xs[4] = {v.x, v.y, v.z, v.w};
#pragma unroll
        for (int kk = 0; kk < 4; ++kk) {
            float xv = xs[kk];
            const float* wr = W1 + (k4 * 4 + kk) * HD;    // uniform row
#pragma unroll
            for (int j = 0; j < HD; ++j) acc[j] = fmaf(xv, wr[j], acc[j]);
        }
    }
    float h1[HD];
#pragma unroll
    for (int j = 0; j < HD; ++j) h1[j] = acc[j] > 0.0f ? acc[j] : 0.0f;

    // ---- layer 2: h2 = relu(h1 @ W2 + b2) ----
    float acc2[HD];
#pragma unroll
    for (int j = 0; j < HD; ++j) acc2[j] = b2[j];         // uniform -> s_load
#pragma unroll
    for (int k = 0; k < HD; ++k) {
        float hk = h1[k];
        const float* wr = W2 + k * HD;                    // uniform row
#pragma unroll
        for (int j = 0; j < HD; ++j) acc2[j] = fmaf(hk, wr[j], acc2[j]);
    }

    // ---- head: out = relu(h2) @ Wfc + bfc ----
    float s = bfc[0];
#pragma unroll
    for (int j = 0; j < HD; ++j) {
        float v = acc2[j] > 0.0f ? acc2[j] : 0.0f;
        s = fmaf(v, Wfc[j], s);                           // uniform -> s_load
    }
    out[node] = s;
}

extern "C" void kernel_launch(void* const* d_in, const int* in_sizes, int n_in,
                              void* d_out, int out_size, void* d_ws, size_t ws_size,
                              hipStream_t stream) {
    const float* x   = (const float*)d_in[0];
    // d_in[1] = edge_index — unused: row==col makes the conv identity+bias.
    const float* W1  = (const float*)d_in[2];
    const float* b1  = (const float*)d_in[3];
    const float* W2  = (const float*)d_in[4];
    const float* b2  = (const float*)d_in[5];
    const float* Wfc = (const float*)d_in[6];
    const float* bfc = (const float*)d_in[7];
    float* out = (float*)d_out;

    const int bs = 256;
    k_mlp<<<(TOT + bs - 1) / bs, bs, 0, stream>>>(x, W1, b1, W2, b2, Wfc, bfc, out);
}

// Round 4
// 22.169 us; speedup vs baseline: 1.9814x; 1.3910x over previous
//
#include <hip/hip_runtime.h>

#define TOT   400000            // B*N total nodes
#define FI    64                // in features
#define HD    16                // hidden dim
#define TILES (TOT / 16)        // 25000 16-node tiles
#define NBLK  2048
#define NWAVE (NBLK * 4)        // 256 threads = 4 waves per block

typedef _Float16 f16x8 __attribute__((ext_vector_type(8)));
typedef float    f32x4 __attribute__((ext_vector_type(4)));

// edge_index.expand(B,2,E).reshape(2,-1) makes row==col elementwise
// (flat idx = b*2E + r*E + e; +8E only shifts b by 4) -> every edge is a
// self-edge -> GCNConv == identity + bias. Network = per-node MLP:
//   out = relu(relu(x@W1+b1)@W2+b2)@Wfc + bfc
//
// Layer 1 and 2 on the matrix pipe via SWAPPED operands:
//   D1 = W1^T(16x64) . X^T(64x16)  -> D1[j][node], two 16x16x32 K-steps
//   D2 = W2^T(16x32,zero-pad) . H1relu^T(32x16,zero-pad) -> D2[j'][node]
// C/D layout (m89-verified): col=lane&15, row=(lane>>4)*4+reg.
// A layout: lane holds A[row=lane&15][k=(lane>>4)*8+i], i=0..7.
// B layout: lane holds B[k=(lane>>4)*8+i][col=lane&15].
// D1 output (node=lane&15, j=hi*4+q) is bpermute-distance from the
// B-fragment layer 2 needs: 8 ds_bpermute + zero-pad for k>=16.
__global__ __launch_bounds__(256) void k_mlp_mfma(
        const float* __restrict__ x,
        const float* __restrict__ W1, const float* __restrict__ b1,
        const float* __restrict__ W2, const float* __restrict__ b2,
        const float* __restrict__ Wfc, const float* __restrict__ bfc,
        float* __restrict__ out) {
    const int lane = threadIdx.x & 63;
    const int n    = lane & 15;      // node-in-tile / D col
    const int hi   = lane >> 4;      // 0..3
    const int wid  = blockIdx.x * 4 + (threadIdx.x >> 6);

    // ---- one-time per wave: weight fragments (VGPR-resident) ----
    // A1 = W1^T: A1[row=n][k=hi*8+i (+32*ks)] = W1[k][n]
    f16x8 a1f[2];
#pragma unroll
    for (int ks = 0; ks < 2; ++ks)
#pragma unroll
        for (int i = 0; i < 8; ++i)
            a1f[ks][i] = (_Float16)W1[(ks * 32 + hi * 8 + i) * HD + n];

    // A2 = W2^T zero-padded to K=32: A2[row=n][k=hi*8+i] = k<16 ? W2[k][n] : 0
    f16x8 a2f;
    if (hi < 2) {
#pragma unroll
        for (int i = 0; i < 8; ++i)
            a2f[i] = (_Float16)W2[(hi * 8 + i) * HD + n];
    } else {
#pragma unroll
        for (int i = 0; i < 8; ++i)
            a2f[i] = (_Float16)0.0f;
    }

    // per-lane bias / head-weight slices (j = hi*4 + q)
    const float4 b1p = *reinterpret_cast<const float4*>(b1 + hi * 4);
    const float4 b2p = *reinterpret_cast<const float4*>(b2 + hi * 4);
    const float4 wfp = *reinterpret_cast<const float4*>(Wfc + hi * 4);
    const float  bf  = bfc[0];

    // bpermute source lanes for assembling layer-2 B-fragment:
    // dest lane needs h1relu[n][j], j = hi*8 + i; source lane = ((j>>2)&3)*16+n
    const int src0 = (((hi * 2)     & 3) * 16 + n) * 4;   // i = 0..3
    const int src1 = (((hi * 2 + 1) & 3) * 16 + n) * 4;   // i = 4..7
    const bool live = (hi < 2);                           // k<16 rows only

    for (int t = wid; t < TILES; t += NWAVE) {
        const float* xrow = x + ((size_t)t * 16 + n) * FI;

        // B1 = X^T: lane holds x[node][hi*8 .. +8] (+32 for K-step 1)
        float4 xa = *reinterpret_cast<const float4*>(xrow + hi * 8);
        float4 xb = *reinterpret_cast<const float4*>(xrow + hi * 8 + 4);
        float4 xc = *reinterpret_cast<const float4*>(xrow + 32 + hi * 8);
        float4 xd = *reinterpret_cast<const float4*>(xrow + 32 + hi * 8 + 4);
        f16x8 bA, bB;
        bA[0] = (_Float16)xa.x; bA[1] = (_Float16)xa.y;
        bA[2] = (_Float16)xa.z; bA[3] = (_Float16)xa.w;
        bA[4] = (_Float16)xb.x; bA[5] = (_Float16)xb.y;
        bA[6] = (_Float16)xb.z; bA[7] = (_Float16)xb.w;
        bB[0] = (_Float16)xc.x; bB[1] = (_Float16)xc.y;
        bB[2] = (_Float16)xc.z; bB[3] = (_Float16)xc.w;
        bB[4] = (_Float16)xd.x; bB[5] = (_Float16)xd.y;
        bB[6] = (_Float16)xd.z; bB[7] = (_Float16)xd.w;

        f32x4 acc = {0.f, 0.f, 0.f, 0.f};
        acc = __builtin_amdgcn_mfma_f32_16x16x32_f16(a1f[0], bA, acc, 0, 0, 0);
        acc = __builtin_amdgcn_mfma_f32_16x16x32_f16(a1f[1], bB, acc, 0, 0, 0);

        // lane holds h1pre[node=n][j=hi*4+q]; bias + relu in f32
        float t0 = fmaxf(acc[0] + b1p.x, 0.f);
        float t1 = fmaxf(acc[1] + b1p.y, 0.f);
        float t2 = fmaxf(acc[2] + b1p.z, 0.f);
        float t3 = fmaxf(acc[3] + b1p.w, 0.f);

        // assemble B2 fragment: B2[k=hi*8+i][n] = h1relu[n][j=hi*8+i] (k<16)
        float g0 = __int_as_float(__builtin_amdgcn_ds_bpermute(src0, __float_as_int(t0)));
        float g1 = __int_as_float(__builtin_amdgcn_ds_bpermute(src0, __float_as_int(t1)));
        float g2 = __int_as_float(__builtin_amdgcn_ds_bpermute(src0, __float_as_int(t2)));
        float g3 = __int_as_float(__builtin_amdgcn_ds_bpermute(src0, __float_as_int(t3)));
        float g4 = __int_as_float(__builtin_amdgcn_ds_bpermute(src1, __float_as_int(t0)));
        float g5 = __int_as_float(__builtin_amdgcn_ds_bpermute(src1, __float_as_int(t1)));
        float g6 = __int_as_float(__builtin_amdgcn_ds_bpermute(src1, __float_as_int(t2)));
        float g7 = __int_as_float(__builtin_amdgcn_ds_bpermute(src1, __float_as_int(t3)));
        f16x8 b2f;
        b2f[0] = (_Float16)(live ? g0 : 0.f);
        b2f[1] = (_Float16)(live ? g1 : 0.f);
        b2f[2] = (_Float16)(live ? g2 : 0.f);
        b2f[3] = (_Float16)(live ? g3 : 0.f);
        b2f[4] = (_Float16)(live ? g4 : 0.f);
        b2f[5] = (_Float16)(live ? g5 : 0.f);
        b2f[6] = (_Float16)(live ? g6 : 0.f);
        b2f[7] = (_Float16)(live ? g7 : 0.f);

        f32x4 acc2 = {0.f, 0.f, 0.f, 0.f};
        acc2 = __builtin_amdgcn_mfma_f32_16x16x32_f16(a2f, b2f, acc2, 0, 0, 0);

        // lane holds h2pre[node=n][j'=hi*4+q]; bias+relu+head partial
        float u0 = fmaxf(acc2[0] + b2p.x, 0.f);
        float u1 = fmaxf(acc2[1] + b2p.y, 0.f);
        float u2 = fmaxf(acc2[2] + b2p.z, 0.f);
        float u3 = fmaxf(acc2[3] + b2p.w, 0.f);
        float s = u0 * wfp.x + u1 * wfp.y + u2 * wfp.z + u3 * wfp.w;
        s += __shfl_xor(s, 16, 64);
        s += __shfl_xor(s, 32, 64);
        if (hi == 0) out[t * 16 + n] = s + bf;
    }
}

extern "C" void kernel_launch(void* const* d_in, const int* in_sizes, int n_in,
                              void* d_out, int out_size, void* d_ws, size_t ws_size,
                              hipStream_t stream) {
    const float* x   = (const float*)d_in[0];
    // d_in[1] = edge_index — unused: row==col makes the conv identity+bias.
    const float* W1  = (const float*)d_in[2];
    const float* b1  = (const float*)d_in[3];
    const float* W2  = (const float*)d_in[4];
    const float* b2  = (const float*)d_in[5];
    const float* Wfc = (const float*)d_in[6];
    const float* bfc = (const float*)d_in[7];
    float* out = (float*)d_out;

    k_mlp_mfma<<<NBLK, 256, 0, stream>>>(x, W1, b1, W2, b2, Wfc, bfc, out);
}